// Round 3
// baseline (321.819 us; speedup 1.0000x reference)
//
#include <hip/hip_runtime.h>

// TransformerBlock: B=8,S=196,D=768,H=12,HD=64,E=8,FF=3072. T = B*S = 1568 tokens.
//
// Exact simplifications:
//  - attention: k,v broadcast across heads -> logits constant over softmax axis
//    -> softmax uniform -> attn_out = tile(v). Wq/bq/Wk/bk/RoPE are dead code.
//  - MoE top-1 = argmax of gating logits (softmax monotone).
//
// R2 structure:
//  - k_pre: fused LN1 + v-proj + (x2 = x+tile(v)) + LN2 + gate argmax + bucketize
//           + out init (x2 + b2[expert]).  196 blocks.
//  - k_plan: 1 block, builds compact work-item lists from cnt[] so GEMM workers
//            have zero empty-block drain.
//  - k_moe_gemm1: BM=64,BN=64,BK=64 grouped GEMM + gelu -> hmid (bf16).
//  - k_moe_gemm2: BM=64,BN=64,BK=64, split-K x4, atomicAdd fp32 into out.

typedef unsigned short u16;
typedef short bf16x8_t __attribute__((ext_vector_type(8)));
typedef short bf16x4_t __attribute__((ext_vector_type(4)));
typedef float f32x4_t  __attribute__((ext_vector_type(4)));

#define T_TOK 1568
#define DM 768
#define HD 64
#define FF 3072
#define NE 8

// workspace layout (16B-aligned)
#define OFF_CNT   0        // 8 ints
#define OFF_N12   32       // 2 ints
#define OFF_ITEM1 64       // up to 200 ints
#define OFF_ITEM2 864      // up to 800 ints
#define OFF_BUCK  4096     // NE*T_TOK ints
#define OFF_H2    54272    // T_TOK*DM u16
#define OFF_HMID  2462720  // T_TOK*FF u16   (ends ~12.1 MB)

__device__ __forceinline__ float bf2f(u16 h) {
    unsigned u = ((unsigned)h) << 16;
    return __builtin_bit_cast(float, u);
}
__device__ __forceinline__ u16 f2bf(float f) {  // round-to-nearest-even
    unsigned u = __builtin_bit_cast(unsigned, f);
    unsigned r = (u + 0x7FFFu + ((u >> 16) & 1u)) >> 16;
    return (u16)r;
}
__device__ __forceinline__ float gelu_f(float x) {
    return 0.5f * x * (1.0f + erff(x * 0.70710678118654752440f));
}

// ---- K1: fused LN1 + vproj + x2/LN2 + gate + out-init (8 tokens/block) ----
__global__ __launch_bounds__(256) void k_pre(
        const float* __restrict__ x,
        const float* __restrict__ g1, const float* __restrict__ b1,
        const float* __restrict__ Wv, const float* __restrict__ bv,
        const float* __restrict__ g2, const float* __restrict__ b2g,
        const float* __restrict__ Wg, const float* __restrict__ bg,
        const float* __restrict__ b2moe,
        u16* __restrict__ h2, float* __restrict__ out,
        int* __restrict__ cnt, int* __restrict__ buck) {
    __shared__ __align__(16) u16 h1s[8 * DM];    // 12 KB (bf16 LN1 output)
    __shared__ float wgs[NE * DM];               // 24 KB (Wg transposed)
    __shared__ float g2s[DM], b2s[DM];           // 6 KB
    __shared__ float ps[4 * 8 * 64];             // 8 KB (vproj partials)
    __shared__ float vsm[8 * 64];                // 2 KB (v per token)
    int tid = threadIdx.x, lane = tid & 63, w = tid >> 6;
    int tb = blockIdx.x * 8;

    for (int idx = tid; idx < NE * DM; idx += 256) {
        int e = idx / DM, c = idx % DM;
        wgs[idx] = Wg[(size_t)c * NE + e];
    }
    for (int idx = tid; idx < DM; idx += 256) { g2s[idx] = g2[idx]; b2s[idx] = b2g[idx]; }

    // phase 1: LN1 for this wave's 2 tokens; keep raw x rows in registers
    float xv[2][12];
#pragma unroll
    for (int ttl = 0; ttl < 2; ttl++) {
        int tl = w * 2 + ttl;
        int t = tb + tl;
        const float* xp = x + (size_t)t * DM;
        float s = 0.0f;
#pragma unroll
        for (int i = 0; i < 12; i++) { float q = xp[lane + 64 * i]; xv[ttl][i] = q; s += q; }
#pragma unroll
        for (int m = 1; m < 64; m <<= 1) s += __shfl_xor(s, m);
        float mu = s * (1.0f / DM);
        float vs = 0.0f;
#pragma unroll
        for (int i = 0; i < 12; i++) { float d = xv[ttl][i] - mu; vs += d * d; }
#pragma unroll
        for (int m = 1; m < 64; m <<= 1) vs += __shfl_xor(vs, m);
        float rs = rsqrtf(vs * (1.0f / DM) + 1e-5f);
#pragma unroll
        for (int i = 0; i < 12; i++) {
            int c = lane + 64 * i;
            h1s[tl * DM + c] = f2bf((xv[ttl][i] - mu) * rs * g1[c] + b1[c]);
        }
    }
    __syncthreads();

    // phase 2: v = h1 @ Wv (wave w covers k in [w*192, w*192+192))
    float acc[8];
#pragma unroll
    for (int tt = 0; tt < 8; tt++) acc[tt] = 0.0f;
    const float* wp = Wv + (size_t)(w * 192) * HD + lane;
    for (int kk = 0; kk < 192; kk += 4) {
        float w0 = wp[(size_t)(kk + 0) * HD];
        float w1 = wp[(size_t)(kk + 1) * HD];
        float w2 = wp[(size_t)(kk + 2) * HD];
        float w3 = wp[(size_t)(kk + 3) * HD];
        int kb = w * 192 + kk;
#pragma unroll
        for (int tt = 0; tt < 8; tt++) {
            bf16x4_t hh = *(const bf16x4_t*)&h1s[tt * DM + kb];
            acc[tt] += bf2f((u16)hh[0]) * w0 + bf2f((u16)hh[1]) * w1 +
                       bf2f((u16)hh[2]) * w2 + bf2f((u16)hh[3]) * w3;
        }
    }
#pragma unroll
    for (int tt = 0; tt < 8; tt++) ps[(w * 8 + tt) * 64 + lane] = acc[tt];
    __syncthreads();
#pragma unroll
    for (int s2 = 0; s2 < 2; s2++) {
        int tt = w * 2 + s2;
        vsm[tt * 64 + lane] = ps[tt * 64 + lane] + ps[(8 + tt) * 64 + lane] +
                              ps[(16 + tt) * 64 + lane] + ps[(24 + tt) * 64 + lane] +
                              bv[lane];
    }
    __syncthreads();

    // phase 3: x2 = x + tile(v); LN2 -> h2; gate argmax; bucket; out init
#pragma unroll
    for (int ttl = 0; ttl < 2; ttl++) {
        int tl = w * 2 + ttl;
        int t = tb + tl;
        float vl = vsm[tl * 64 + lane];
        float x2v[12];
        float s = 0.0f;
#pragma unroll
        for (int i = 0; i < 12; i++) { float q = xv[ttl][i] + vl; x2v[i] = q; s += q; }
#pragma unroll
        for (int m = 1; m < 64; m <<= 1) s += __shfl_xor(s, m);
        float mu = s * (1.0f / DM);
        float vs = 0.0f;
#pragma unroll
        for (int i = 0; i < 12; i++) { float d = x2v[i] - mu; vs += d * d; }
#pragma unroll
        for (int m = 1; m < 64; m <<= 1) vs += __shfl_xor(vs, m);
        float rs = rsqrtf(vs * (1.0f / DM) + 1e-5f);
        float le[NE];
#pragma unroll
        for (int e = 0; e < NE; e++) le[e] = 0.0f;
        u16* h2p = h2 + (size_t)t * DM;
#pragma unroll
        for (int i = 0; i < 12; i++) {
            int c = lane + 64 * i;
            float h = (x2v[i] - mu) * rs * g2s[c] + b2s[c];
            h2p[c] = f2bf(h);
#pragma unroll
            for (int e = 0; e < NE; e++) le[e] += h * wgs[e * DM + c];
        }
#pragma unroll
        for (int e = 0; e < NE; e++) {
#pragma unroll
            for (int m = 1; m < 64; m <<= 1) le[e] += __shfl_xor(le[e], m);
        }
        float best = le[0] + bg[0]; int be = 0;
#pragma unroll
        for (int e = 1; e < NE; e++) {
            float q = le[e] + bg[e];
            if (q > best) { best = q; be = e; }   // strict > == first-max (jnp.argmax)
        }
        if (lane == 0) {
            int pos = atomicAdd(&cnt[be], 1);
            buck[be * T_TOK + pos] = t;
        }
        float* op = out + (size_t)t * DM;
        const float* bp = b2moe + (size_t)be * DM;
#pragma unroll
        for (int i = 0; i < 12; i++) {
            int c = lane + 64 * i;
            op[c] = x2v[i] + bp[c];
        }
    }
}

// ---- K2: planner -> compact work-item lists (zero drain for GEMM workers) ----
__global__ void k_plan(const int* __restrict__ cnt, int* __restrict__ n12,
                       int* __restrict__ item1, int* __restrict__ item2) {
    if (threadIdx.x == 0) {
        int n1 = 0, n2 = 0;
        for (int e = 0; e < NE; e++) {
            int mts = (cnt[e] + 63) >> 6;
            for (int mt = 0; mt < mts; mt++) {
                int code = e * 64 + mt;
                item1[n1++] = code;
                for (int kc = 0; kc < 4; kc++) item2[n2++] = code * 4 + kc;
            }
        }
        n12[0] = n1; n12[1] = n2;
    }
}

// ---- K3: grouped GEMM1 + gelu: hmid = gelu(h2 @ W1[e] + b1[e]) ----
// BM=64, BN=64, BK=64; 4 waves, wave -> 16-row strip x 64 cols.
__global__ __launch_bounds__(256) void k_moe_gemm1(
        const u16* __restrict__ h2, const float* __restrict__ W1,
        const float* __restrict__ b1, const int* __restrict__ cnt,
        const int* __restrict__ n12, const int* __restrict__ item1,
        const int* __restrict__ buck, u16* __restrict__ hmid) {
    int nt = blockIdx.x, n0 = nt * 64;
    int n1 = n12[0];
    int tid = threadIdx.x, lane = tid & 63, wid = tid >> 6;
    int arow = tid >> 3, ac = tid & 7;        // A: row 0..31 (+32), col-chunk 0..7
    int bn = tid & 63, bkg = tid >> 6;        // B: col, k-group of 16
    int lr = lane & 15, q = lane >> 4;
    __shared__ __align__(16) u16 As[64 * 72];  // 9 KB
    __shared__ __align__(16) u16 Bs[64 * 72];  // 9 KB [n][k]

    for (int it = blockIdx.y; it < n1; it += gridDim.y) {
        int code = item1[it];
        int e = code >> 6, mt = code & 63;
        int cnte = cnt[e], m0 = mt * 64;
        const float* W1e = W1 + (size_t)e * DM * FF;
        int atok[2];
#pragma unroll
        for (int j = 0; j < 2; j++) {
            int i = m0 + arow + 32 * j;
            atok[j] = (i < cnte) ? buck[e * T_TOK + i] : -1;
        }
        f32x4_t acc[4];
#pragma unroll
        for (int ni = 0; ni < 4; ni++) acc[ni] = (f32x4_t){0.f, 0.f, 0.f, 0.f};

        bf16x8_t a_pre[2];
        float b_pre[16];
#pragma unroll
        for (int j = 0; j < 2; j++) {
            bf16x8_t v = {0, 0, 0, 0, 0, 0, 0, 0};
            if (atok[j] >= 0) v = *(const bf16x8_t*)&h2[(size_t)atok[j] * DM + ac * 8];
            a_pre[j] = v;
        }
        {
            const float* bp = W1e + (size_t)(bkg * 16) * FF + n0 + bn;
#pragma unroll
            for (int kk = 0; kk < 16; kk++) b_pre[kk] = bp[(size_t)kk * FF];
        }
        const int NK = DM / 64;   // 12
        for (int kt = 0; kt < NK; kt++) {
            __syncthreads();
#pragma unroll
            for (int j = 0; j < 2; j++)
                *(bf16x8_t*)&As[(arow + 32 * j) * 72 + ac * 8] = a_pre[j];
            {
                bf16x8_t p0, p1;
#pragma unroll
                for (int kk = 0; kk < 8; kk++) {
                    p0[kk] = (short)f2bf(b_pre[kk]);
                    p1[kk] = (short)f2bf(b_pre[kk + 8]);
                }
                *(bf16x8_t*)&Bs[bn * 72 + bkg * 16] = p0;
                *(bf16x8_t*)&Bs[bn * 72 + bkg * 16 + 8] = p1;
            }
            __syncthreads();
            if (kt + 1 < NK) {
                int k0 = (kt + 1) * 64;
#pragma unroll
                for (int j = 0; j < 2; j++) {
                    bf16x8_t v = {0, 0, 0, 0, 0, 0, 0, 0};
                    if (atok[j] >= 0)
                        v = *(const bf16x8_t*)&h2[(size_t)atok[j] * DM + k0 + ac * 8];
                    a_pre[j] = v;
                }
                const float* bp = W1e + (size_t)(k0 + bkg * 16) * FF + n0 + bn;
#pragma unroll
                for (int kk = 0; kk < 16; kk++) b_pre[kk] = bp[(size_t)kk * FF];
            }
#pragma unroll
            for (int s = 0; s < 2; s++) {
                bf16x8_t af = *(const bf16x8_t*)&As[(wid * 16 + lr) * 72 + s * 32 + q * 8];
#pragma unroll
                for (int ni = 0; ni < 4; ni++) {
                    bf16x8_t bfr = *(const bf16x8_t*)&Bs[(ni * 16 + lr) * 72 + s * 32 + q * 8];
                    acc[ni] = __builtin_amdgcn_mfma_f32_16x16x32_bf16(af, bfr, acc[ni], 0, 0, 0);
                }
            }
        }
        float bias[4];
#pragma unroll
        for (int ni = 0; ni < 4; ni++) bias[ni] = b1[(size_t)e * FF + n0 + ni * 16 + lr];
#pragma unroll
        for (int r = 0; r < 4; r++) {
            int i = m0 + wid * 16 + q * 4 + r;
            if (i < cnte) {
                int t = buck[e * T_TOK + i];
                size_t base = (size_t)t * FF + n0;
#pragma unroll
                for (int ni = 0; ni < 4; ni++)
                    hmid[base + ni * 16 + lr] = f2bf(gelu_f(acc[ni][r] + bias[ni]));
            }
        }
    }
}

// ---- K4: grouped GEMM2, split-K x4: out += hmid @ W2[e] (atomic fp32) ----
__global__ __launch_bounds__(256) void k_moe_gemm2(
        const u16* __restrict__ hmid, const float* __restrict__ W2,
        const int* __restrict__ cnt, const int* __restrict__ n12,
        const int* __restrict__ item2, const int* __restrict__ buck,
        float* __restrict__ out) {
    int nt = blockIdx.x, n0 = nt * 64;
    int n2 = n12[1];
    int tid = threadIdx.x, lane = tid & 63, wid = tid >> 6;
    int arow = tid >> 3, ac = tid & 7;
    int bn = tid & 63, bkg = tid >> 6;
    int lr = lane & 15, q = lane >> 4;
    __shared__ __align__(16) u16 As[64 * 72];
    __shared__ __align__(16) u16 Bs[64 * 72];

    for (int it = blockIdx.y; it < n2; it += gridDim.y) {
        int code2 = item2[it];
        int kc = code2 & 3, code = code2 >> 2;
        int e = code >> 6, mt = code & 63;
        int cnte = cnt[e], m0 = mt * 64;
        int kbase = kc * (FF / 4);
        const float* W2e = W2 + (size_t)e * FF * DM;
        int atok[2];
#pragma unroll
        for (int j = 0; j < 2; j++) {
            int i = m0 + arow + 32 * j;
            atok[j] = (i < cnte) ? buck[e * T_TOK + i] : -1;
        }
        f32x4_t acc[4];
#pragma unroll
        for (int ni = 0; ni < 4; ni++) acc[ni] = (f32x4_t){0.f, 0.f, 0.f, 0.f};

        bf16x8_t a_pre[2];
        float b_pre[16];
#pragma unroll
        for (int j = 0; j < 2; j++) {
            bf16x8_t v = {0, 0, 0, 0, 0, 0, 0, 0};
            if (atok[j] >= 0)
                v = *(const bf16x8_t*)&hmid[(size_t)atok[j] * FF + kbase + ac * 8];
            a_pre[j] = v;
        }
        {
            const float* bp = W2e + (size_t)(kbase + bkg * 16) * DM + n0 + bn;
#pragma unroll
            for (int kk = 0; kk < 16; kk++) b_pre[kk] = bp[(size_t)kk * DM];
        }
        const int NK = (FF / 4) / 64;   // 12
        for (int kt = 0; kt < NK; kt++) {
            __syncthreads();
#pragma unroll
            for (int j = 0; j < 2; j++)
                *(bf16x8_t*)&As[(arow + 32 * j) * 72 + ac * 8] = a_pre[j];
            {
                bf16x8_t p0, p1;
#pragma unroll
                for (int kk = 0; kk < 8; kk++) {
                    p0[kk] = (short)f2bf(b_pre[kk]);
                    p1[kk] = (short)f2bf(b_pre[kk + 8]);
                }
                *(bf16x8_t*)&Bs[bn * 72 + bkg * 16] = p0;
                *(bf16x8_t*)&Bs[bn * 72 + bkg * 16 + 8] = p1;
            }
            __syncthreads();
            if (kt + 1 < NK) {
                int k0 = kbase + (kt + 1) * 64;
#pragma unroll
                for (int j = 0; j < 2; j++) {
                    bf16x8_t v = {0, 0, 0, 0, 0, 0, 0, 0};
                    if (atok[j] >= 0)
                        v = *(const bf16x8_t*)&hmid[(size_t)atok[j] * FF + k0 + ac * 8];
                    a_pre[j] = v;
                }
                const float* bp = W2e + (size_t)(k0 + bkg * 16) * DM + n0 + bn;
#pragma unroll
                for (int kk = 0; kk < 16; kk++) b_pre[kk] = bp[(size_t)kk * DM];
            }
#pragma unroll
            for (int s = 0; s < 2; s++) {
                bf16x8_t af = *(const bf16x8_t*)&As[(wid * 16 + lr) * 72 + s * 32 + q * 8];
#pragma unroll
                for (int ni = 0; ni < 4; ni++) {
                    bf16x8_t bfr = *(const bf16x8_t*)&Bs[(ni * 16 + lr) * 72 + s * 32 + q * 8];
                    acc[ni] = __builtin_amdgcn_mfma_f32_16x16x32_bf16(af, bfr, acc[ni], 0, 0, 0);
                }
            }
        }
#pragma unroll
        for (int r = 0; r < 4; r++) {
            int i = m0 + wid * 16 + q * 4 + r;
            if (i < cnte) {
                int t = buck[e * T_TOK + i];
                size_t base = (size_t)t * DM + n0;
#pragma unroll
                for (int ni = 0; ni < 4; ni++)
                    atomicAdd(&out[base + ni * 16 + lr], acc[ni][r]);
            }
        }
    }
}

extern "C" void kernel_launch(void* const* d_in, const int* in_sizes, int n_in,
                              void* d_out, int out_size, void* d_ws, size_t ws_size,
                              hipStream_t stream) {
    const float* x    = (const float*)d_in[0];
    const float* ln1g = (const float*)d_in[1];
    const float* ln1b = (const float*)d_in[2];
    // d_in[3..6] = Wq,bq,Wk,bk: dead code
    const float* Wv   = (const float*)d_in[7];
    const float* bv   = (const float*)d_in[8];
    const float* ln2g = (const float*)d_in[9];
    const float* ln2b = (const float*)d_in[10];
    const float* Wg   = (const float*)d_in[11];
    const float* bg   = (const float*)d_in[12];
    const float* W1   = (const float*)d_in[13];
    const float* b1   = (const float*)d_in[14];
    const float* W2   = (const float*)d_in[15];
    const float* b2   = (const float*)d_in[16];

    char* ws = (char*)d_ws;
    int*   cnt   = (int*)(ws + OFF_CNT);
    int*   n12   = (int*)(ws + OFF_N12);
    int*   item1 = (int*)(ws + OFF_ITEM1);
    int*   item2 = (int*)(ws + OFF_ITEM2);
    int*   buck  = (int*)(ws + OFF_BUCK);
    u16*   h2    = (u16*)(ws + OFF_H2);
    u16*   hmid  = (u16*)(ws + OFF_HMID);
    float* out   = (float*)d_out;

    hipMemsetAsync(cnt, 0, 16 * sizeof(int), stream);
    k_pre<<<T_TOK / 8, 256, 0, stream>>>(x, ln1g, ln1b, Wv, bv, ln2g, ln2b,
                                         Wg, bg, b2, h2, out, cnt, buck);
    k_plan<<<1, 64, 0, stream>>>(cnt, n12, item1, item2);
    k_moe_gemm1<<<dim3(FF / 64, 32), 256, 0, stream>>>(h2, W1, b1, cnt, n12,
                                                       item1, buck, hmid);
    k_moe_gemm2<<<dim3(DM / 64, 128), 256, 0, stream>>>(hmid, W2, cnt, n12,
                                                        item2, buck, out);
}